// Round 4
// baseline (182.259 us; speedup 1.0000x reference)
//
#include <hip/hip_runtime.h>

#define B_   16
#define C_   64
#define N_   2048
#define M_   (B_ * N_)     // 32768 points
#define K_   20
#define KS_  20
#define OC_  64
#define NWAVE2 8192        // waves in k_points (2048 blocks x 4 waves)
#define NBLK2  2048        // blocks in k_points

// ---------------------------------------------------------------------------
// K1: P[m][o] = sum_c W2[o][c]*flat[m][c];  Q[m][o] = sum_c (W1-W2)[o][c]*flat[m][c]
// wave = 64 lanes, lane = o. Weights in 128 VGPRs, feature broadcast via
// readlane. 4 accumulator chains to cover FMA latency.
// ---------------------------------------------------------------------------
__global__ __launch_bounds__(256) void k_project(
    const float* __restrict__ feat,     // [B][C][N]
    const float* __restrict__ conv_w,   // [OC][2C]
    float* __restrict__ pq)             // [M][128]
{
    const int lane = threadIdx.x & 63;
    const int wg   = blockIdx.x * 4 + (threadIdx.x >> 6);   // 0..2047
    float w2[64], wd[64];
    const float4* cw4 = (const float4*)conv_w;
    #pragma unroll
    for (int j = 0; j < 16; ++j) {
        float4 a = cw4[lane * 32 + j];        // W1 chunk
        float4 b = cw4[lane * 32 + 16 + j];   // W2 chunk
        w2[4*j+0] = b.x; w2[4*j+1] = b.y; w2[4*j+2] = b.z; w2[4*j+3] = b.w;
        wd[4*j+0] = a.x - b.x; wd[4*j+1] = a.y - b.y;
        wd[4*j+2] = a.z - b.z; wd[4*j+3] = a.w - b.w;
    }
    const int m0 = wg * 16;
    int b0 = m0 >> 11, p0 = m0 & 2047;
    float fv = feat[((size_t)(b0 * 64 + lane)) * 2048 + p0];
    for (int mi = 0; mi < 16; ++mi) {
        const int m = m0 + mi;
        float fnext = 0.f;
        if (mi < 15) {
            const int mn = m + 1;
            fnext = feat[((size_t)((mn >> 11) * 64 + lane)) * 2048 + (mn & 2047)];
        }
        float p0a = 0.f, p1a = 0.f, q0a = 0.f, q1a = 0.f;
        #pragma unroll
        for (int c = 0; c < 32; ++c) {
            float f0 = __int_as_float(
                __builtin_amdgcn_readlane(__float_as_int(fv), c));
            float f1 = __int_as_float(
                __builtin_amdgcn_readlane(__float_as_int(fv), c + 32));
            p0a = fmaf(w2[c], f0, p0a);
            p1a = fmaf(w2[c + 32], f1, p1a);
            q0a = fmaf(wd[c], f0, q0a);
            q1a = fmaf(wd[c + 32], f1, q1a);
        }
        pq[(size_t)m * 128 + lane]      = p0a + p1a;
        pq[(size_t)m * 128 + 64 + lane] = q0a + q1a;
        fv = fnext;
    }
}

// ---------------------------------------------------------------------------
// K2 support: perm row broadcast via SMEM (s_load_dwordx16 -> SGPRs).
// v_fma_f32 takes one SGPR operand directly, so a wave-uniform perm element
// costs ZERO VALU instructions (vs v_readlane: 400 VALU ops/point, which
// was the measured 63us VALU-issue bottleneck; the LDS variant equivalently
// saturated the DS pipe -- both broadcast paths measured identical 63us).
// Chunk = 4 perm rows = 80 floats = 5 x s_load_dwordx16 (80 SGPRs live,
// serialized load->wait->compute to stay under the 102-SGPR budget; the
// per-chunk lgkmcnt(0) drain is covered by 8-wave TLP).
// NOTE: local names sA..sE chosen to avoid collision with the dimension
// macros (B_, C_, ...) -- that collision was round 3's compile failure.
// ---------------------------------------------------------------------------
typedef float f16v __attribute__((ext_vector_type(16)));

template<int V, int I>
__device__ __forceinline__ float selv(const f16v& a, const f16v& b,
                                      const f16v& c, const f16v& d,
                                      const f16v& e) {
    if constexpr (V == 0) return a[I];
    else if constexpr (V == 1) return b[I];
    else if constexpr (V == 2) return c[I];
    else if constexpr (V == 3) return d[I];
    else return e[I];
}

// one perm row (20 FMAs into acc[0..19]); KK = row index within chunk (0..3)
template<int KK, bool INIT>
__device__ __forceinline__ void rowfma(float t, float bias, float* acc,
    const f16v& a, const f16v& b, const f16v& c,
    const f16v& d, const f16v& e)
{
    #define RS_(S) { constexpr int e_ = KK * 20 + (S); \
        const float w_ = selv<e_ / 16, e_ % 16>(a, b, c, d, e); \
        acc[S] = fmaf(t, w_, INIT ? bias : acc[S]); }
    RS_(0)  RS_(1)  RS_(2)  RS_(3)  RS_(4)
    RS_(5)  RS_(6)  RS_(7)  RS_(8)  RS_(9)
    RS_(10) RS_(11) RS_(12) RS_(13) RS_(14)
    RS_(15) RS_(16) RS_(17) RS_(18) RS_(19)
    #undef RS_
}

// load 4 perm rows (chunk CC) into 80 SGPRs, wait, run 4 rows of FMAs.
// The s_waitcnt asm ties the loaded tuples as in/out operands so consumers
// have a true dataflow dependency on the wait (rule: compiler may otherwise
// hoist register-only ops past an asm wait).
#define CHUNK(CC, INIT0) { \
    f16v sA, sB, sC, sD, sE; \
    asm volatile("s_load_dwordx16 %0, %1, %2" : "=s"(sA) : "s"(psrc), "n"((CC)*320 +   0)); \
    asm volatile("s_load_dwordx16 %0, %1, %2" : "=s"(sB) : "s"(psrc), "n"((CC)*320 +  64)); \
    asm volatile("s_load_dwordx16 %0, %1, %2" : "=s"(sC) : "s"(psrc), "n"((CC)*320 + 128)); \
    asm volatile("s_load_dwordx16 %0, %1, %2" : "=s"(sD) : "s"(psrc), "n"((CC)*320 + 192)); \
    asm volatile("s_load_dwordx16 %0, %1, %2" : "=s"(sE) : "s"(psrc), "n"((CC)*320 + 256)); \
    asm volatile("s_waitcnt lgkmcnt(0)" \
        : "+s"(sA), "+s"(sB), "+s"(sC), "+s"(sD), "+s"(sE)); \
    rowfma<0, INIT0>(pk[(CC)*4+0] + q, bias, acc, sA, sB, sC, sD, sE); \
    rowfma<1, false>(pk[(CC)*4+1] + q, bias, acc, sA, sB, sC, sD, sE); \
    rowfma<2, false>(pk[(CC)*4+2] + q, bias, acc, sA, sB, sC, sD, sE); \
    rowfma<3, false>(pk[(CC)*4+3] + q, bias, acc, sA, sB, sC, sD, sE); }

// ---------------------------------------------------------------------------
// K2: per point n (wave = point, lane = o):
//   pk[k] = P[idx[n,k]][o] + Q[idx[n,0]][o]
//   acc[s] = b[o] + sum_k pk[k]*perm[n][k][s];  pre[n][o] = max_s acc[s]
// Gathers issued per point (21 coalesced 256B loads, saddr form via uniform
// readlane'd indices); latency hidden by 8-wave TLP (VGPR ~55).
// ---------------------------------------------------------------------------
__global__ __launch_bounds__(256) void k_points(
    const float* __restrict__ pq,        // [M][128]
    const int*   __restrict__ nidx,      // [M][K]
    const float* __restrict__ perm,      // [M][K][KS]
    const float* __restrict__ conv_b,    // [OC]
    float* __restrict__ pre,             // [M][OC]
    float* __restrict__ partials)        // [NBLK2][128]
{
    const int tid  = threadIdx.x;
    const int lane = tid & 63;
    const int w    = tid >> 6;
    const int wg   = (int)blockIdx.x * 4 + w;               // wave id 0..8191
    const int wgu  = __builtin_amdgcn_readfirstlane(wg);    // uniform copy

    const float bias = conv_b[lane];
    float sum = 0.f, sumsq = 0.f;

    int iv = 0;
    if (lane < 20) iv = nidx[(size_t)wg * K_ + lane];

    for (int it = 0; it < 4; ++it) {
        const int n  = wg  + NWAVE2 * it;
        const int nu = wgu + NWAVE2 * it;
        // broadcast idx values to SGPRs (readlane results are uniform ->
        // SALU address math + saddr-form gathers)
        int ik[20];
        #pragma unroll
        for (int k = 0; k < 20; ++k) ik[k] = __builtin_amdgcn_readlane(iv, k);
        float q = pq[(size_t)ik[0] * 128 + 64 + lane];
        float pk[20];
        #pragma unroll
        for (int k = 0; k < 20; ++k) pk[k] = pq[(size_t)ik[k] * 128 + lane];
        // prefetch next point's idx row (stays in flight across the FMAs)
        if (it < 3) {
            const int nn = n + NWAVE2;
            if (lane < 20) iv = nidx[(size_t)nn * K_ + lane];
        }
        const float* psrc = perm + (size_t)nu * 400;  // uniform -> SGPR pair

        float acc[20];
        CHUNK(0, true)
        CHUNK(1, false)
        CHUNK(2, false)
        CHUNK(3, false)
        CHUNK(4, false)

        float mv = acc[0];
        #pragma unroll
        for (int s = 1; s < 20; ++s) mv = fmaxf(mv, acc[s]);
        pre[(size_t)n * 64 + lane] = mv;
        sum += mv;
        sumsq = fmaf(mv, mv, sumsq);
    }

    // block-level BN partial reduction: 4MB -> 1MB partials
    __shared__ float red[512];
    red[w * 128 + lane]      = sum;
    red[w * 128 + 64 + lane] = sumsq;
    __syncthreads();
    if (tid < 128) {
        float s = red[tid] + red[128 + tid] + red[256 + tid] + red[384 + tid];
        partials[(size_t)blockIdx.x * 128 + tid] = s;
    }
}

#undef CHUNK

// ---------------------------------------------------------------------------
// K2b: reduce partials per channel, fold BN+gamma/beta into scale/shift.
// ---------------------------------------------------------------------------
__global__ __launch_bounds__(256) void k_stats(
    const float* __restrict__ partials,  // [NBLK2][128]
    const float* __restrict__ gamma,
    const float* __restrict__ beta,
    float* __restrict__ stats)           // [128]
{
    const int ch  = blockIdx.x;          // 0..63
    const int tid = threadIdx.x;
    double s = 0.0, s2 = 0.0;
    for (int w = tid; w < NBLK2; w += 256) {
        s  += (double)partials[(size_t)w * 128 + ch];
        s2 += (double)partials[(size_t)w * 128 + 64 + ch];
    }
    __shared__ double sh_s[256];
    __shared__ double sh_q[256];
    sh_s[tid] = s; sh_q[tid] = s2;
    __syncthreads();
    for (int off = 128; off > 0; off >>= 1) {
        if (tid < off) { sh_s[tid] += sh_s[tid + off]; sh_q[tid] += sh_q[tid + off]; }
        __syncthreads();
    }
    if (tid == 0) {
        const double inv_n = 1.0 / (double)M_;
        double mean = sh_s[0] * inv_n;
        double var  = sh_q[0] * inv_n - mean * mean;
        double inv  = 1.0 / sqrt(var + 1e-5);
        double sc   = (double)gamma[ch] * inv;
        stats[ch]      = (float)sc;
        stats[64 + ch] = (float)((double)beta[ch] - mean * sc);
    }
}

// ---------------------------------------------------------------------------
// K3: y = pre*scale + shift, transposed [M][OC] -> [B][OC][N] via LDS 64x65.
// ---------------------------------------------------------------------------
__global__ __launch_bounds__(256) void k_apply(
    const float* __restrict__ pre,     // [M][OC]
    const float* __restrict__ stats,   // [128]
    float* __restrict__ out)           // [B][OC][N]
{
    __shared__ float tile[64 * 65];
    __shared__ float scl[64];
    __shared__ float shf[64];
    const int tid = threadIdx.x;
    if (tid < 64)       scl[tid]      = stats[tid];
    else if (tid < 128) shf[tid - 64] = stats[tid];
    __syncthreads();
    const int b  = blockIdx.x >> 5;
    const int pt = (blockIdx.x & 31) * 64;
    const int c  = tid & 63;
    const int r0 = tid >> 6;
    #pragma unroll
    for (int i = 0; i < 16; ++i) {
        const int r = i * 4 + r0;
        float v = pre[((size_t)(b * 2048 + pt + r)) * 64 + c];
        tile[c * 65 + r] = fmaf(v, scl[c], shf[c]);
    }
    __syncthreads();
    #pragma unroll
    for (int i = 0; i < 16; ++i) {
        const int o = i * 4 + r0;
        out[((size_t)(b * 64 + o)) * 2048 + pt + c] = tile[o * 65 + c];
    }
}

extern "C" void kernel_launch(void* const* d_in, const int* in_sizes, int n_in,
                              void* d_out, int out_size, void* d_ws, size_t ws_size,
                              hipStream_t stream) {
    const float* feat   = (const float*)d_in[0];
    const int*   nidx   = (const int*)  d_in[1];
    const float* perm   = (const float*)d_in[2];
    const float* conv_w = (const float*)d_in[3];
    const float* conv_b = (const float*)d_in[4];
    const float* gamma  = (const float*)d_in[5];
    const float* beta   = (const float*)d_in[6];
    float* out = (float*)d_out;

    char* ws = (char*)d_ws;
    float* pq       = (float*)ws;                                    // 16 MiB
    float* pre      = (float*)(ws + (size_t)M_ * 128 * 4);           //  8 MiB
    float* partials = (float*)(ws + (size_t)M_ * 128 * 4
                                  + (size_t)M_ * 64 * 4);            //  1 MiB
    float* stats    = (float*)(ws + (size_t)M_ * 128 * 4
                                  + (size_t)M_ * 64 * 4
                                  + (size_t)NBLK2 * 128 * 4);        // 512 B

    hipLaunchKernelGGL(k_project, dim3(512),  dim3(256), 0, stream, feat, conv_w, pq);
    hipLaunchKernelGGL(k_points,  dim3(2048), dim3(256), 0, stream, pq, nidx, perm,
                       conv_b, pre, partials);
    hipLaunchKernelGGL(k_stats,   dim3(64),   dim3(256), 0, stream, partials, gamma,
                       beta, stats);
    hipLaunchKernelGGL(k_apply,   dim3(512),  dim3(256), 0, stream, pre, stats, out);
}

// Round 5
// 179.001 us; speedup vs baseline: 1.0182x; 1.0182x over previous
//
#include <hip/hip_runtime.h>

#define B_   16
#define C_   64
#define N_   2048
#define M_   (B_ * N_)     // 32768 points
#define K_   20
#define KS_  20
#define OC_  64
#define NWAVE2 8192        // waves in k_points (2048 blocks x 4 waves)
#define NBLK2  2048        // blocks in k_points

// ---------------------------------------------------------------------------
// K1: P[m][o] = sum_c W2[o][c]*flat[m][c];  Q[m][o] = sum_c (W1-W2)[o][c]*flat[m][c]
// ---------------------------------------------------------------------------
__global__ __launch_bounds__(256) void k_project(
    const float* __restrict__ feat,     // [B][C][N]
    const float* __restrict__ conv_w,   // [OC][2C]
    float* __restrict__ pq)             // [M][128]
{
    const int lane = threadIdx.x & 63;
    const int wg   = blockIdx.x * 4 + (threadIdx.x >> 6);   // 0..2047
    float w2[64], wd[64];
    const float4* cw4 = (const float4*)conv_w;
    #pragma unroll
    for (int j = 0; j < 16; ++j) {
        float4 a = cw4[lane * 32 + j];        // W1 chunk
        float4 b = cw4[lane * 32 + 16 + j];   // W2 chunk
        w2[4*j+0] = b.x; w2[4*j+1] = b.y; w2[4*j+2] = b.z; w2[4*j+3] = b.w;
        wd[4*j+0] = a.x - b.x; wd[4*j+1] = a.y - b.y;
        wd[4*j+2] = a.z - b.z; wd[4*j+3] = a.w - b.w;
    }
    const int m0 = wg * 16;
    int b0 = m0 >> 11, p0 = m0 & 2047;
    float fv = feat[((size_t)(b0 * 64 + lane)) * 2048 + p0];
    for (int mi = 0; mi < 16; ++mi) {
        const int m = m0 + mi;
        float fnext = 0.f;
        if (mi < 15) {
            const int mn = m + 1;
            fnext = feat[((size_t)((mn >> 11) * 64 + lane)) * 2048 + (mn & 2047)];
        }
        float p0a = 0.f, p1a = 0.f, q0a = 0.f, q1a = 0.f;
        #pragma unroll
        for (int c = 0; c < 32; ++c) {
            float f0 = __int_as_float(
                __builtin_amdgcn_readlane(__float_as_int(fv), c));
            float f1 = __int_as_float(
                __builtin_amdgcn_readlane(__float_as_int(fv), c + 32));
            p0a = fmaf(w2[c], f0, p0a);
            p1a = fmaf(w2[c + 32], f1, p1a);
            q0a = fmaf(wd[c], f0, q0a);
            q1a = fmaf(wd[c + 32], f1, q1a);
        }
        pq[(size_t)m * 128 + lane]      = p0a + p1a;
        pq[(size_t)m * 128 + 64 + lane] = q0a + q1a;
        fv = fnext;
    }
}

// ---------------------------------------------------------------------------
// K2 support: perm row broadcast via SMEM (s_load_dwordx16 -> 80 SGPRs per
// 4-row chunk; v_fma_f32 reads the SGPR operand directly -> zero VALU cost).
// Gathers: issued via VOLATILE asm one point ahead (compiler cannot sink
// them, unlike the round-2 C++ attempt which regalloc rematerialized away).
// All vmem in the loop is asm -> we own the vmcnt bookkeeping exactly.
// ---------------------------------------------------------------------------
typedef float f16v __attribute__((ext_vector_type(16)));

template<int V, int I>
__device__ __forceinline__ float selv(const f16v& a, const f16v& b,
                                      const f16v& c, const f16v& d,
                                      const f16v& e) {
    if constexpr (V == 0) return a[I];
    else if constexpr (V == 1) return b[I];
    else if constexpr (V == 2) return c[I];
    else if constexpr (V == 3) return d[I];
    else return e[I];
}

// one perm row (20 FMAs into acc[0..19]); KK = row index within chunk (0..3)
template<int KK, bool INIT>
__device__ __forceinline__ void rowfma(float t, float bias, float* acc,
    const f16v& a, const f16v& b, const f16v& c,
    const f16v& d, const f16v& e)
{
    #define RS_(S) { constexpr int e_ = KK * 20 + (S); \
        const float w_ = selv<e_ / 16, e_ % 16>(a, b, c, d, e); \
        acc[S] = fmaf(t, w_, INIT ? bias : acc[S]); }
    RS_(0)  RS_(1)  RS_(2)  RS_(3)  RS_(4)
    RS_(5)  RS_(6)  RS_(7)  RS_(8)  RS_(9)
    RS_(10) RS_(11) RS_(12) RS_(13) RS_(14)
    RS_(15) RS_(16) RS_(17) RS_(18) RS_(19)
    #undef RS_
}

// load 4 perm rows (chunk CC) into 80 SGPRs, data-tied wait, 4 rows of FMAs.
// t = gar[row] + gar[20] (gathered pk + q) -- same values/order as before.
#define CHUNK(gar, CC, INIT0) { \
    f16v sA, sB, sC, sD, sE; \
    asm volatile("s_load_dwordx16 %0, %1, %2" : "=s"(sA) : "s"(psrc), "n"((CC)*320 +   0)); \
    asm volatile("s_load_dwordx16 %0, %1, %2" : "=s"(sB) : "s"(psrc), "n"((CC)*320 +  64)); \
    asm volatile("s_load_dwordx16 %0, %1, %2" : "=s"(sC) : "s"(psrc), "n"((CC)*320 + 128)); \
    asm volatile("s_load_dwordx16 %0, %1, %2" : "=s"(sD) : "s"(psrc), "n"((CC)*320 + 192)); \
    asm volatile("s_load_dwordx16 %0, %1, %2" : "=s"(sE) : "s"(psrc), "n"((CC)*320 + 256)); \
    asm volatile("s_waitcnt lgkmcnt(0)" \
        : "+s"(sA), "+s"(sB), "+s"(sC), "+s"(sD), "+s"(sE)); \
    rowfma<0, INIT0>(gar[(CC)*4+0] + gar[20], bias, acc, sA, sB, sC, sD, sE); \
    rowfma<1, false>(gar[(CC)*4+1] + gar[20], bias, acc, sA, sB, sC, sD, sE); \
    rowfma<2, false>(gar[(CC)*4+2] + gar[20], bias, acc, sA, sB, sC, sD, sE); \
    rowfma<3, false>(gar[(CC)*4+3] + gar[20], bias, acc, sA, sB, sC, sD, sE); }

// issue ALL memory for one point: q (row ik0, +256B) then pk[0..19].
// volatile asm -> issue position is pinned; compiler does not track these
// loads, so no spurious compiler waitcnt can drain the pipeline.
__device__ __forceinline__ void issue_gathers(
    const float* __restrict__ pqt, int ivreg, int voff, float (&g)[21])
{
    #pragma unroll
    for (int k = 0; k < 20; ++k) {
        const int iku = __builtin_amdgcn_readlane(ivreg, k);
        const float* sp = pqt + (size_t)(unsigned)iku * 128u;
        if (k == 0)
            asm volatile("global_load_dword %0, %1, %2 offset:256"
                         : "=v"(g[20]) : "v"(voff), "s"(sp));
        asm volatile("global_load_dword %0, %1, %2"
                     : "=v"(g[k]) : "v"(voff), "s"(sp));
    }
}

// counted wait, data-tied to all 21 destination regs; sched_barrier stops
// the scheduler from hoisting consumers above it (rule #18).
#define WAITG(g, CNTTXT) do { \
    asm volatile("s_waitcnt vmcnt(" CNTTXT ")" : \
        "+v"(g[0]),"+v"(g[1]),"+v"(g[2]),"+v"(g[3]),"+v"(g[4]), \
        "+v"(g[5]),"+v"(g[6]),"+v"(g[7]),"+v"(g[8]),"+v"(g[9]), \
        "+v"(g[10]),"+v"(g[11]),"+v"(g[12]),"+v"(g[13]),"+v"(g[14]), \
        "+v"(g[15]),"+v"(g[16]),"+v"(g[17]),"+v"(g[18]),"+v"(g[19]), \
        "+v"(g[20])); \
    __builtin_amdgcn_sched_barrier(0); \
} while (0)

#define COMPUTE(gar, NU) { \
    const float* psrc = perm + (size_t)(NU) * 400; \
    float acc[20]; \
    CHUNK(gar, 0, true) \
    CHUNK(gar, 1, false) \
    CHUNK(gar, 2, false) \
    CHUNK(gar, 3, false) \
    CHUNK(gar, 4, false) \
    float mv = acc[0]; \
    mv = fmaxf(mv, acc[1]);  mv = fmaxf(mv, acc[2]);  mv = fmaxf(mv, acc[3]); \
    mv = fmaxf(mv, acc[4]);  mv = fmaxf(mv, acc[5]);  mv = fmaxf(mv, acc[6]); \
    mv = fmaxf(mv, acc[7]);  mv = fmaxf(mv, acc[8]);  mv = fmaxf(mv, acc[9]); \
    mv = fmaxf(mv, acc[10]); mv = fmaxf(mv, acc[11]); mv = fmaxf(mv, acc[12]); \
    mv = fmaxf(mv, acc[13]); mv = fmaxf(mv, acc[14]); mv = fmaxf(mv, acc[15]); \
    mv = fmaxf(mv, acc[16]); mv = fmaxf(mv, acc[17]); mv = fmaxf(mv, acc[18]); \
    mv = fmaxf(mv, acc[19]); \
    const float* pdst = pre + (size_t)(NU) * 64; \
    asm volatile("global_store_dword %0, %1, %2" \
                 :: "v"(voff), "v"(mv), "s"(pdst)); \
    sum += mv; \
    sumsq = fmaf(mv, mv, sumsq); }

// ---------------------------------------------------------------------------
// K2: per point n (wave = point, lane = o):
//   pk[k] = P[idx[n,k]][o] + Q[idx[n,0]][o]
//   acc[s] = b[o] + sum_k pk[k]*perm[n][k][s];  pre[n][o] = max_s acc[s]
// Asm-pipelined: gathers for point n+1 stay in flight across point n's
// whole FMA+SMEM block (~1500cy >> L3 ~600cy). vmem issue order is
// g0,g1,st0,g2,st1,g3,st2,st3 -> waits 21,22,22,1 retire exactly one
// 21-load batch each.
// ---------------------------------------------------------------------------
__global__ __launch_bounds__(256) void k_points(
    const float* __restrict__ pq,        // [M][128]
    const int*   __restrict__ nidx,      // [M][K]
    const float* __restrict__ perm,      // [M][K][KS]
    const float* __restrict__ conv_b,    // [OC]
    float* __restrict__ pre,             // [M][OC]
    float* __restrict__ partials)        // [NBLK2][128]
{
    const int tid  = threadIdx.x;
    const int lane = tid & 63;
    const int w    = tid >> 6;
    const int wg   = (int)blockIdx.x * 4 + w;               // wave id 0..8191
    const int wgu  = __builtin_amdgcn_readfirstlane(wg);    // uniform copy
    const int voff = lane * 4;

    float bias = conv_b[lane];
    float sum = 0.f, sumsq = 0.f;

    int iv0 = 0, iv1 = 0, iv2 = 0, iv3 = 0;
    if (lane < 20) {
        iv0 = nidx[(size_t)wgu * K_ + lane];
        iv1 = nidx[((size_t)wgu +     NWAVE2) * K_ + lane];
        iv2 = nidx[((size_t)wgu + 2 * NWAVE2) * K_ + lane];
        iv3 = nidx[((size_t)wgu + 3 * NWAVE2) * K_ + lane];
    }
    // drain ALL compiler-tracked vmem before the first asm gather so the
    // hand-counted vmcnt bookkeeping below is exact.
    asm volatile("s_waitcnt vmcnt(0)"
        : "+v"(bias), "+v"(iv0), "+v"(iv1), "+v"(iv2), "+v"(iv3));
    __builtin_amdgcn_sched_barrier(0);

    float gA[21], gB[21];
    issue_gathers(pq, iv0, voff, gA);        // g0
    issue_gathers(pq, iv1, voff, gB);        // g1
    WAITG(gA, "21");
    COMPUTE(gA, wgu)                         // point 0 (+store0)
    issue_gathers(pq, iv2, voff, gA);        // g2
    WAITG(gB, "22");
    COMPUTE(gB, wgu + NWAVE2)                // point 1 (+store1)
    issue_gathers(pq, iv3, voff, gB);        // g3
    WAITG(gA, "22");
    COMPUTE(gA, wgu + 2 * NWAVE2)            // point 2 (+store2)
    WAITG(gB, "1");
    COMPUTE(gB, wgu + 3 * NWAVE2)            // point 3

    // block-level BN partial reduction: 4MB -> 1MB partials
    __shared__ float red[512];
    red[w * 128 + lane]      = sum;
    red[w * 128 + 64 + lane] = sumsq;
    __syncthreads();
    if (tid < 128) {
        float s = red[tid] + red[128 + tid] + red[256 + tid] + red[384 + tid];
        partials[(size_t)blockIdx.x * 128 + tid] = s;
    }
}

#undef COMPUTE
#undef WAITG
#undef CHUNK

// ---------------------------------------------------------------------------
// K2b: reduce partials per channel, fold BN+gamma/beta into scale/shift.
// ---------------------------------------------------------------------------
__global__ __launch_bounds__(256) void k_stats(
    const float* __restrict__ partials,  // [NBLK2][128]
    const float* __restrict__ gamma,
    const float* __restrict__ beta,
    float* __restrict__ stats)           // [128]
{
    const int ch  = blockIdx.x;          // 0..63
    const int tid = threadIdx.x;
    double s = 0.0, s2 = 0.0;
    for (int w = tid; w < NBLK2; w += 256) {
        s  += (double)partials[(size_t)w * 128 + ch];
        s2 += (double)partials[(size_t)w * 128 + 64 + ch];
    }
    __shared__ double sh_s[256];
    __shared__ double sh_q[256];
    sh_s[tid] = s; sh_q[tid] = s2;
    __syncthreads();
    for (int off = 128; off > 0; off >>= 1) {
        if (tid < off) { sh_s[tid] += sh_s[tid + off]; sh_q[tid] += sh_q[tid + off]; }
        __syncthreads();
    }
    if (tid == 0) {
        const double inv_n = 1.0 / (double)M_;
        double mean = sh_s[0] * inv_n;
        double var  = sh_q[0] * inv_n - mean * mean;
        double inv  = 1.0 / sqrt(var + 1e-5);
        double sc   = (double)gamma[ch] * inv;
        stats[ch]      = (float)sc;
        stats[64 + ch] = (float)((double)beta[ch] - mean * sc);
    }
}

// ---------------------------------------------------------------------------
// K3: y = pre*scale + shift, transposed [M][OC] -> [B][OC][N] via LDS 64x65.
// ---------------------------------------------------------------------------
__global__ __launch_bounds__(256) void k_apply(
    const float* __restrict__ pre,     // [M][OC]
    const float* __restrict__ stats,   // [128]
    float* __restrict__ out)           // [B][OC][N]
{
    __shared__ float tile[64 * 65];
    __shared__ float scl[64];
    __shared__ float shf[64];
    const int tid = threadIdx.x;
    if (tid < 64)       scl[tid]      = stats[tid];
    else if (tid < 128) shf[tid - 64] = stats[tid];
    __syncthreads();
    const int b  = blockIdx.x >> 5;
    const int pt = (blockIdx.x & 31) * 64;
    const int c  = tid & 63;
    const int r0 = tid >> 6;
    #pragma unroll
    for (int i = 0; i < 16; ++i) {
        const int r = i * 4 + r0;
        float v = pre[((size_t)(b * 2048 + pt + r)) * 64 + c];
        tile[c * 65 + r] = fmaf(v, scl[c], shf[c]);
    }
    __syncthreads();
    #pragma unroll
    for (int i = 0; i < 16; ++i) {
        const int o = i * 4 + r0;
        out[((size_t)(b * 64 + o)) * 2048 + pt + c] = tile[o * 65 + c];
    }
}

extern "C" void kernel_launch(void* const* d_in, const int* in_sizes, int n_in,
                              void* d_out, int out_size, void* d_ws, size_t ws_size,
                              hipStream_t stream) {
    const float* feat   = (const float*)d_in[0];
    const int*   nidx   = (const int*)  d_in[1];
    const float* perm   = (const float*)d_in[2];
    const float* conv_w = (const float*)d_in[3];
    const float* conv_b = (const float*)d_in[4];
    const float* gamma  = (const float*)d_in[5];
    const float* beta   = (const float*)d_in[6];
    float* out = (float*)d_out;

    char* ws = (char*)d_ws;
    float* pq       = (float*)ws;                                    // 16 MiB
    float* pre      = (float*)(ws + (size_t)M_ * 128 * 4);           //  8 MiB
    float* partials = (float*)(ws + (size_t)M_ * 128 * 4
                                  + (size_t)M_ * 64 * 4);            //  1 MiB
    float* stats    = (float*)(ws + (size_t)M_ * 128 * 4
                                  + (size_t)M_ * 64 * 4
                                  + (size_t)NBLK2 * 128 * 4);        // 512 B

    hipLaunchKernelGGL(k_project, dim3(512),  dim3(256), 0, stream, feat, conv_w, pq);
    hipLaunchKernelGGL(k_points,  dim3(2048), dim3(256), 0, stream, pq, nidx, perm,
                       conv_b, pre, partials);
    hipLaunchKernelGGL(k_stats,   dim3(64),   dim3(256), 0, stream, partials, gamma,
                       beta, stats);
    hipLaunchKernelGGL(k_apply,   dim3(512),  dim3(256), 0, stream, pre, stats, out);
}

// Round 6
// 176.978 us; speedup vs baseline: 1.0298x; 1.0114x over previous
//
#include <hip/hip_runtime.h>
#include <hip/hip_fp16.h>

#define B_   16
#define C_   64
#define N_   2048
#define M_   (B_ * N_)     // 32768 points
#define K_   20
#define KS_  20
#define OC_  64
#define NWAVE2 8192        // waves in k_points (2048 blocks x 4 waves)
#define NBLK2  2048        // blocks in k_points

// ---------------------------------------------------------------------------
// K1: P[m][o] = sum_c W2[o][c]*flat[m][c];  Q[m][o] = sum_c (W1-W2)[o][c]*flat[m][c]
// P stored fp16 (hot gather table, 4 MiB = 1 L2 line per gather, L2-resident);
// Q stays fp32 (cold, 1 gather/point).
// ---------------------------------------------------------------------------
__global__ __launch_bounds__(256) void k_project(
    const float* __restrict__ feat,     // [B][C][N]
    const float* __restrict__ conv_w,   // [OC][2C]
    __half* __restrict__ ph,            // [M][64] fp16 P
    float*  __restrict__ qf)            // [M][64] fp32 Q
{
    const int lane = threadIdx.x & 63;
    const int wg   = blockIdx.x * 4 + (threadIdx.x >> 6);   // 0..2047
    float w2[64], wd[64];
    const float4* cw4 = (const float4*)conv_w;
    #pragma unroll
    for (int j = 0; j < 16; ++j) {
        float4 a = cw4[lane * 32 + j];        // W1 chunk
        float4 b = cw4[lane * 32 + 16 + j];   // W2 chunk
        w2[4*j+0] = b.x; w2[4*j+1] = b.y; w2[4*j+2] = b.z; w2[4*j+3] = b.w;
        wd[4*j+0] = a.x - b.x; wd[4*j+1] = a.y - b.y;
        wd[4*j+2] = a.z - b.z; wd[4*j+3] = a.w - b.w;
    }
    const int m0 = wg * 16;
    int b0 = m0 >> 11, p0 = m0 & 2047;
    float fv = feat[((size_t)(b0 * 64 + lane)) * 2048 + p0];
    for (int mi = 0; mi < 16; ++mi) {
        const int m = m0 + mi;
        float fnext = 0.f;
        if (mi < 15) {
            const int mn = m + 1;
            fnext = feat[((size_t)((mn >> 11) * 64 + lane)) * 2048 + (mn & 2047)];
        }
        float p0a = 0.f, p1a = 0.f, q0a = 0.f, q1a = 0.f;
        #pragma unroll
        for (int c = 0; c < 32; ++c) {
            float f0 = __int_as_float(
                __builtin_amdgcn_readlane(__float_as_int(fv), c));
            float f1 = __int_as_float(
                __builtin_amdgcn_readlane(__float_as_int(fv), c + 32));
            p0a = fmaf(w2[c], f0, p0a);
            p1a = fmaf(w2[c + 32], f1, p1a);
            q0a = fmaf(wd[c], f0, q0a);
            q1a = fmaf(wd[c + 32], f1, q1a);
        }
        ph[(size_t)m * 64 + lane] = __float2half(p0a + p1a);   // RN-even
        qf[(size_t)m * 64 + lane] = q0a + q1a;
        fv = fnext;
    }
}

// ---------------------------------------------------------------------------
// K2 support. Perm row broadcast via SMEM (s_load_dwordx16 -> 80 SGPRs per
// 4-row chunk; v_fma_f32 reads the SGPR operand directly).
// Gathers: volatile-asm pipelined one point ahead. R5 proved the pipeline is
// real (21-42 loads pinned in flight) yet timing was invariant at 63-65us
// across 4 variants => per-CU outstanding-miss cap (~16 MSHRs):
//   4032 miss-lines/CU x 250ns / 16 = 63us. The ONLY lever is fewer
//   miss-lines / more L2 hits => fp16 P table (1 line/gather, 4MiB hot set).
// ---------------------------------------------------------------------------
typedef float f16v __attribute__((ext_vector_type(16)));

__device__ __forceinline__ float h2f(int u) {      // bit-exact fp16 -> fp32
    __half_raw r; r.x = (unsigned short)u;
    return __half2float(__half(r));
}

template<int V, int I>
__device__ __forceinline__ float selv(const f16v& a, const f16v& b,
                                      const f16v& c, const f16v& d,
                                      const f16v& e) {
    if constexpr (V == 0) return a[I];
    else if constexpr (V == 1) return b[I];
    else if constexpr (V == 2) return c[I];
    else if constexpr (V == 3) return d[I];
    else return e[I];
}

// one perm row (20 FMAs into acc[0..19]); KK = row index within chunk (0..3)
template<int KK, bool INIT>
__device__ __forceinline__ void rowfma(float t, float bias, float* acc,
    const f16v& a, const f16v& b, const f16v& c,
    const f16v& d, const f16v& e)
{
    #define RS_(S) { constexpr int e_ = KK * 20 + (S); \
        const float w_ = selv<e_ / 16, e_ % 16>(a, b, c, d, e); \
        acc[S] = fmaf(t, w_, INIT ? bias : acc[S]); }
    RS_(0)  RS_(1)  RS_(2)  RS_(3)  RS_(4)
    RS_(5)  RS_(6)  RS_(7)  RS_(8)  RS_(9)
    RS_(10) RS_(11) RS_(12) RS_(13) RS_(14)
    RS_(15) RS_(16) RS_(17) RS_(18) RS_(19)
    #undef RS_
}

// load 4 perm rows (chunk CC) into 80 SGPRs, data-tied wait, 4 rows of FMAs.
#define CHUNK(tkk, CC, INIT0) { \
    f16v sA, sB, sC, sD, sE; \
    asm volatile("s_load_dwordx16 %0, %1, %2" : "=s"(sA) : "s"(psrc), "n"((CC)*320 +   0)); \
    asm volatile("s_load_dwordx16 %0, %1, %2" : "=s"(sB) : "s"(psrc), "n"((CC)*320 +  64)); \
    asm volatile("s_load_dwordx16 %0, %1, %2" : "=s"(sC) : "s"(psrc), "n"((CC)*320 + 128)); \
    asm volatile("s_load_dwordx16 %0, %1, %2" : "=s"(sD) : "s"(psrc), "n"((CC)*320 + 192)); \
    asm volatile("s_load_dwordx16 %0, %1, %2" : "=s"(sE) : "s"(psrc), "n"((CC)*320 + 256)); \
    asm volatile("s_waitcnt lgkmcnt(0)" \
        : "+s"(sA), "+s"(sB), "+s"(sC), "+s"(sD), "+s"(sE)); \
    rowfma<0, INIT0>(tkk[(CC)*4+0], bias, acc, sA, sB, sC, sD, sE); \
    rowfma<1, false>(tkk[(CC)*4+1], bias, acc, sA, sB, sC, sD, sE); \
    rowfma<2, false>(tkk[(CC)*4+2], bias, acc, sA, sB, sC, sD, sE); \
    rowfma<3, false>(tkk[(CC)*4+3], bias, acc, sA, sB, sC, sD, sE); }

// issue ALL memory for one point: q (fp32, row ik0) then pk[0..19] (fp16).
// volatile asm -> issue position pinned; compiler tracks no vmem here.
__device__ __forceinline__ void issue_gathers(
    const __half* __restrict__ pht, const float* __restrict__ qft,
    int ivreg, int voff2, int voff4, int (&g)[21])
{
    {
        const int ik0 = __builtin_amdgcn_readlane(ivreg, 0);
        const float* spq = qft + (size_t)(unsigned)ik0 * 64u;
        asm volatile("global_load_dword %0, %1, %2"
                     : "=v"(g[20]) : "v"(voff4), "s"(spq));
    }
    #pragma unroll
    for (int k = 0; k < 20; ++k) {
        const int iku = __builtin_amdgcn_readlane(ivreg, k);
        const __half* sp = pht + (size_t)(unsigned)iku * 64u;
        asm volatile("global_load_ushort %0, %1, %2"
                     : "=v"(g[k]) : "v"(voff2), "s"(sp));
    }
}

// counted wait, data-tied to all 21 destination regs; sched_barrier stops
// the scheduler from hoisting consumers above it (rule #18).
#define WAITG(g, CNTTXT) do { \
    asm volatile("s_waitcnt vmcnt(" CNTTXT ")" : \
        "+v"(g[0]),"+v"(g[1]),"+v"(g[2]),"+v"(g[3]),"+v"(g[4]), \
        "+v"(g[5]),"+v"(g[6]),"+v"(g[7]),"+v"(g[8]),"+v"(g[9]), \
        "+v"(g[10]),"+v"(g[11]),"+v"(g[12]),"+v"(g[13]),"+v"(g[14]), \
        "+v"(g[15]),"+v"(g[16]),"+v"(g[17]),"+v"(g[18]),"+v"(g[19]), \
        "+v"(g[20])); \
    __builtin_amdgcn_sched_barrier(0); \
} while (0)

#define COMPUTE(gar, NU) { \
    const float* psrc = perm + (size_t)(NU) * 400; \
    const float qv = __int_as_float(gar[20]); \
    float tk[20]; \
    tk[0]  = h2f(gar[0])  + qv; tk[1]  = h2f(gar[1])  + qv; \
    tk[2]  = h2f(gar[2])  + qv; tk[3]  = h2f(gar[3])  + qv; \
    tk[4]  = h2f(gar[4])  + qv; tk[5]  = h2f(gar[5])  + qv; \
    tk[6]  = h2f(gar[6])  + qv; tk[7]  = h2f(gar[7])  + qv; \
    tk[8]  = h2f(gar[8])  + qv; tk[9]  = h2f(gar[9])  + qv; \
    tk[10] = h2f(gar[10]) + qv; tk[11] = h2f(gar[11]) + qv; \
    tk[12] = h2f(gar[12]) + qv; tk[13] = h2f(gar[13]) + qv; \
    tk[14] = h2f(gar[14]) + qv; tk[15] = h2f(gar[15]) + qv; \
    tk[16] = h2f(gar[16]) + qv; tk[17] = h2f(gar[17]) + qv; \
    tk[18] = h2f(gar[18]) + qv; tk[19] = h2f(gar[19]) + qv; \
    float acc[20]; \
    CHUNK(tk, 0, true) \
    CHUNK(tk, 1, false) \
    CHUNK(tk, 2, false) \
    CHUNK(tk, 3, false) \
    CHUNK(tk, 4, false) \
    float mv = acc[0]; \
    mv = fmaxf(mv, acc[1]);  mv = fmaxf(mv, acc[2]);  mv = fmaxf(mv, acc[3]); \
    mv = fmaxf(mv, acc[4]);  mv = fmaxf(mv, acc[5]);  mv = fmaxf(mv, acc[6]); \
    mv = fmaxf(mv, acc[7]);  mv = fmaxf(mv, acc[8]);  mv = fmaxf(mv, acc[9]); \
    mv = fmaxf(mv, acc[10]); mv = fmaxf(mv, acc[11]); mv = fmaxf(mv, acc[12]); \
    mv = fmaxf(mv, acc[13]); mv = fmaxf(mv, acc[14]); mv = fmaxf(mv, acc[15]); \
    mv = fmaxf(mv, acc[16]); mv = fmaxf(mv, acc[17]); mv = fmaxf(mv, acc[18]); \
    mv = fmaxf(mv, acc[19]); \
    const float* pdst = pre + (size_t)(NU) * 64; \
    asm volatile("global_store_dword %0, %1, %2" \
                 :: "v"(voff4), "v"(mv), "s"(pdst)); \
    sum += mv; \
    sumsq = fmaf(mv, mv, sumsq); }

// ---------------------------------------------------------------------------
// K2: per point n (wave = point, lane = o):
//   pk[k] = P[idx[n,k]][o] + Q[idx[n,0]][o]
//   acc[s] = b[o] + sum_k pk[k]*perm[n][k][s];  pre[n][o] = max_s acc[s]
// vmem issue order: g0,g1,st0,g2,st1,g3,st2,st3 -> waits 21,22,22,1.
// ---------------------------------------------------------------------------
__global__ __launch_bounds__(256) void k_points(
    const __half* __restrict__ ph,       // [M][64] fp16 P
    const float*  __restrict__ qf,       // [M][64] fp32 Q
    const int*    __restrict__ nidx,     // [M][K]
    const float*  __restrict__ perm,     // [M][K][KS]
    const float*  __restrict__ conv_b,   // [OC]
    float* __restrict__ pre,             // [M][OC]
    float* __restrict__ partials)        // [NBLK2][128]
{
    const int tid  = threadIdx.x;
    const int lane = tid & 63;
    const int w    = tid >> 6;
    const int wg   = (int)blockIdx.x * 4 + w;               // wave id 0..8191
    const int wgu  = __builtin_amdgcn_readfirstlane(wg);    // uniform copy
    const int voff4 = lane * 4;
    const int voff2 = lane * 2;

    float bias = conv_b[lane];
    float sum = 0.f, sumsq = 0.f;

    int iv0 = 0, iv1 = 0, iv2 = 0, iv3 = 0;
    if (lane < 20) {
        iv0 = nidx[(size_t)wgu * K_ + lane];
        iv1 = nidx[((size_t)wgu +     NWAVE2) * K_ + lane];
        iv2 = nidx[((size_t)wgu + 2 * NWAVE2) * K_ + lane];
        iv3 = nidx[((size_t)wgu + 3 * NWAVE2) * K_ + lane];
    }
    // drain ALL compiler-tracked vmem before the first asm gather so the
    // hand-counted vmcnt bookkeeping below is exact.
    asm volatile("s_waitcnt vmcnt(0)"
        : "+v"(bias), "+v"(iv0), "+v"(iv1), "+v"(iv2), "+v"(iv3));
    __builtin_amdgcn_sched_barrier(0);

    int gA[21], gB[21];
    issue_gathers(ph, qf, iv0, voff2, voff4, gA);   // g0
    issue_gathers(ph, qf, iv1, voff2, voff4, gB);   // g1
    WAITG(gA, "21");
    COMPUTE(gA, wgu)                                // point 0 (+store0)
    issue_gathers(ph, qf, iv2, voff2, voff4, gA);   // g2
    WAITG(gB, "22");
    COMPUTE(gB, wgu + NWAVE2)                       // point 1 (+store1)
    issue_gathers(ph, qf, iv3, voff2, voff4, gB);   // g3
    WAITG(gA, "22");
    COMPUTE(gA, wgu + 2 * NWAVE2)                   // point 2 (+store2)
    WAITG(gB, "1");
    COMPUTE(gB, wgu + 3 * NWAVE2)                   // point 3

    // block-level BN partial reduction
    __shared__ float red[512];
    red[w * 128 + lane]      = sum;
    red[w * 128 + 64 + lane] = sumsq;
    __syncthreads();
    if (tid < 128) {
        float s = red[tid] + red[128 + tid] + red[256 + tid] + red[384 + tid];
        partials[(size_t)blockIdx.x * 128 + tid] = s;
    }
}

#undef COMPUTE
#undef WAITG
#undef CHUNK

// ---------------------------------------------------------------------------
// K2b: reduce partials per channel, fold BN+gamma/beta into scale/shift.
// ---------------------------------------------------------------------------
__global__ __launch_bounds__(256) void k_stats(
    const float* __restrict__ partials,  // [NBLK2][128]
    const float* __restrict__ gamma,
    const float* __restrict__ beta,
    float* __restrict__ stats)           // [128]
{
    const int ch  = blockIdx.x;          // 0..63
    const int tid = threadIdx.x;
    double s = 0.0, s2 = 0.0;
    for (int w = tid; w < NBLK2; w += 256) {
        s  += (double)partials[(size_t)w * 128 + ch];
        s2 += (double)partials[(size_t)w * 128 + 64 + ch];
    }
    __shared__ double sh_s[256];
    __shared__ double sh_q[256];
    sh_s[tid] = s; sh_q[tid] = s2;
    __syncthreads();
    for (int off = 128; off > 0; off >>= 1) {
        if (tid < off) { sh_s[tid] += sh_s[tid + off]; sh_q[tid] += sh_q[tid + off]; }
        __syncthreads();
    }
    if (tid == 0) {
        const double inv_n = 1.0 / (double)M_;
        double mean = sh_s[0] * inv_n;
        double var  = sh_q[0] * inv_n - mean * mean;
        double inv  = 1.0 / sqrt(var + 1e-5);
        double sc   = (double)gamma[ch] * inv;
        stats[ch]      = (float)sc;
        stats[64 + ch] = (float)((double)beta[ch] - mean * sc);
    }
}

// ---------------------------------------------------------------------------
// K3: y = pre*scale + shift, transposed [M][OC] -> [B][OC][N] via LDS 64x65.
// ---------------------------------------------------------------------------
__global__ __launch_bounds__(256) void k_apply(
    const float* __restrict__ pre,     // [M][OC]
    const float* __restrict__ stats,   // [128]
    float* __restrict__ out)           // [B][OC][N]
{
    __shared__ float tile[64 * 65];
    __shared__ float scl[64];
    __shared__ float shf[64];
    const int tid = threadIdx.x;
    if (tid < 64)       scl[tid]      = stats[tid];
    else if (tid < 128) shf[tid - 64] = stats[tid];
    __syncthreads();
    const int b  = blockIdx.x >> 5;
    const int pt = (blockIdx.x & 31) * 64;
    const int c  = tid & 63;
    const int r0 = tid >> 6;
    #pragma unroll
    for (int i = 0; i < 16; ++i) {
        const int r = i * 4 + r0;
        float v = pre[((size_t)(b * 2048 + pt + r)) * 64 + c];
        tile[c * 65 + r] = fmaf(v, scl[c], shf[c]);
    }
    __syncthreads();
    #pragma unroll
    for (int i = 0; i < 16; ++i) {
        const int o = i * 4 + r0;
        out[((size_t)(b * 64 + o)) * 2048 + pt + c] = tile[o * 65 + c];
    }
}

extern "C" void kernel_launch(void* const* d_in, const int* in_sizes, int n_in,
                              void* d_out, int out_size, void* d_ws, size_t ws_size,
                              hipStream_t stream) {
    const float* feat   = (const float*)d_in[0];
    const int*   nidx   = (const int*)  d_in[1];
    const float* perm   = (const float*)d_in[2];
    const float* conv_w = (const float*)d_in[3];
    const float* conv_b = (const float*)d_in[4];
    const float* gamma  = (const float*)d_in[5];
    const float* beta   = (const float*)d_in[6];
    float* out = (float*)d_out;

    char* ws = (char*)d_ws;
    __half* ph      = (__half*)ws;                                   //  4 MiB
    float*  qf      = (float*)(ws + (size_t)M_ * 64 * 2);            //  8 MiB
    float*  pre     = (float*)(ws + (size_t)M_ * 64 * 2
                                  + (size_t)M_ * 64 * 4);            //  8 MiB
    float*  partials= (float*)(ws + (size_t)M_ * 64 * 2
                                  + (size_t)M_ * 64 * 4 * 2);        //  1 MiB
    float*  stats   = (float*)(ws + (size_t)M_ * 64 * 2
                                  + (size_t)M_ * 64 * 4 * 2
                                  + (size_t)NBLK2 * 128 * 4);        // 512 B

    hipLaunchKernelGGL(k_project, dim3(512),  dim3(256), 0, stream, feat, conv_w,
                       ph, qf);
    hipLaunchKernelGGL(k_points,  dim3(2048), dim3(256), 0, stream, ph, qf, nidx,
                       perm, conv_b, pre, partials);
    hipLaunchKernelGGL(k_stats,   dim3(64),   dim3(256), 0, stream, partials, gamma,
                       beta, stats);
    hipLaunchKernelGGL(k_apply,   dim3(512),  dim3(256), 0, stream, pre, stats, out);
}